// Round 1
// baseline (83.665 us; speedup 1.0000x reference)
//
#include <hip/hip_runtime.h>

// Gaussian RBF soft-histogram:
//   out[b,o,p] = sum_j exp( -(x[b,j,p] - c[o,j])^2 / (2*w[o,j]^2) )
// x: [B=8, CIN=8, H*W=65536] f32; c,w: [COUT=16, CIN=8] f32; out: [B=8, COUT=16, HW] f32
//
// Strategy: 1 thread = 4 consecutive pixels (float4). Read x once (8x dwordx4),
// compute all 16 outputs, store after each o to keep accumulator pressure low.
// Constants staged to LDS as (center, -log2e/(2w^2)) so inner loop is
// sub/mul/mul/v_exp_f32/add. exp(t) computed as exp2(t*log2e) with log2e folded
// into the width constant. Direct (x-c)^2 form (no polynomial expansion) to
// avoid catastrophic cancellation when bin_widths ~ N(0,1) is tiny.

constexpr int CIN  = 8;
constexpr int COUT = 16;
constexpr int HW   = 256 * 256;   // 65536
constexpr int BATCH = 8;
constexpr int HW4  = HW / 4;      // 16384 float4 per plane

__global__ __launch_bounds__(256) void rbf_hist_kernel(
    const float* __restrict__ x,
    const float* __restrict__ centers,
    const float* __restrict__ widths,
    float* __restrict__ out)
{
    __shared__ float2 s_cn[COUT * CIN];   // (center, negk) where negk = -log2e/(2 w^2)

    const int tid = threadIdx.x;
    if (tid < COUT * CIN) {
        float w = widths[tid];
        float negk = -1.4426950408889634f / (2.0f * w * w);
        s_cn[tid] = make_float2(centers[tid], negk);
    }
    __syncthreads();

    // global thread id over B*HW/4 pixel-quads
    const int t  = blockIdx.x * 256 + tid;      // 0 .. 131071
    const int b  = t >> 14;                     // t / HW4
    const int s4 = t & (HW4 - 1);               // t % HW4  (4 | HW so all 4 pixels share b)

    const float4* __restrict__ xv = (const float4*)x;
    float4* __restrict__ ov = (float4*)out;

    // Load this thread's 8 input channels (x read exactly once from HBM)
    float4 xr[CIN];
#pragma unroll
    for (int j = 0; j < CIN; ++j) {
        xr[j] = xv[(b * CIN + j) * HW4 + s4];
    }

#pragma unroll 4
    for (int o = 0; o < COUT; ++o) {
        float4 acc = make_float4(0.f, 0.f, 0.f, 0.f);
#pragma unroll
        for (int j = 0; j < CIN; ++j) {
            float2 cn = s_cn[o * CIN + j];
            const float c  = cn.x;
            const float nk = cn.y;
            float d0 = xr[j].x - c;
            float d1 = xr[j].y - c;
            float d2 = xr[j].z - c;
            float d3 = xr[j].w - c;
            acc.x += __builtin_amdgcn_exp2f((nk * d0) * d0);
            acc.y += __builtin_amdgcn_exp2f((nk * d1) * d1);
            acc.z += __builtin_amdgcn_exp2f((nk * d2) * d2);
            acc.w += __builtin_amdgcn_exp2f((nk * d3) * d3);
        }
        ov[(b * COUT + o) * HW4 + s4] = acc;
    }
}

extern "C" void kernel_launch(void* const* d_in, const int* in_sizes, int n_in,
                              void* d_out, int out_size, void* d_ws, size_t ws_size,
                              hipStream_t stream) {
    const float* x       = (const float*)d_in[0];
    const float* centers = (const float*)d_in[1];
    const float* widths  = (const float*)d_in[2];
    float* out           = (float*)d_out;

    const int total_threads = BATCH * HW4;          // 131072
    const int block = 256;
    const int grid  = total_threads / block;        // 512

    rbf_hist_kernel<<<grid, block, 0, stream>>>(x, centers, widths, out);
}

// Round 2
// 82.297 us; speedup vs baseline: 1.0166x; 1.0166x over previous
//
#include <hip/hip_runtime.h>

// Gaussian RBF soft-histogram:
//   out[b,o,p] = sum_j exp( -(x[b,j,p] - c[o,j])^2 / (2*w[o,j]^2) )
// x: [B=8, CIN=8, HW=65536] f32; c,w: [COUT=16, CIN=8]; out: [B=8, COUT=16, HW] f32
//
// R2: latency/occupancy fix. R1 (4 pixels/thread, float4) gave only 2048 waves
// = 2 waves/SIMD — issue demand is only ~6.8us chip-wide but 83.7us measured,
// i.e. ~92% stall that 2 waves/SIMD can't hide (exp pipe latency, ds_read
// lgkm waits, initial HBM latency). This version: 1 pixel/thread -> 8192 waves
// = 8 waves/SIMD (HW max), __launch_bounds__(256,8) caps VGPR at 64.
// x still read exactly once (8 dword loads/thread, coalesced 256B/wave).
// Constants in LDS as (center, -log2e/(2w^2)); wave-uniform reads = broadcast,
// conflict-free. Direct (x-c)^2 form kept for numerical safety vs tiny widths.

constexpr int CIN   = 8;
constexpr int COUT  = 16;
constexpr int HW    = 256 * 256;   // 65536
constexpr int BATCH = 8;

__global__ __launch_bounds__(256, 8) void rbf_hist_kernel(
    const float* __restrict__ x,
    const float* __restrict__ centers,
    const float* __restrict__ widths,
    float* __restrict__ out)
{
    __shared__ float2 s_cn[COUT * CIN];   // (center, negk), negk = -log2e/(2 w^2)

    const int tid = threadIdx.x;
    if (tid < COUT * CIN) {
        float w = widths[tid];
        float negk = -1.4426950408889634f / (2.0f * w * w);
        s_cn[tid] = make_float2(centers[tid], negk);
    }
    __syncthreads();

    const int t = blockIdx.x * 256 + tid;     // 0 .. B*HW-1 (524287)
    const int b = t >> 16;                    // t / HW
    const int p = t & (HW - 1);               // t % HW

    // Load this thread's 8 input channels (x read exactly once from HBM)
    const float* __restrict__ xb = x + (b * CIN) * HW + p;
    float xr[CIN];
#pragma unroll
    for (int j = 0; j < CIN; ++j) {
        xr[j] = xb[j * HW];
    }

    float* __restrict__ ob = out + (b * COUT) * HW + p;

#pragma unroll 2
    for (int o = 0; o < COUT; ++o) {
        float acc = 0.f;
#pragma unroll
        for (int j = 0; j < CIN; ++j) {
            const float2 cn = s_cn[o * CIN + j];
            const float d = xr[j] - cn.x;
            acc += __builtin_amdgcn_exp2f((cn.y * d) * d);
        }
        ob[o * HW] = acc;
    }
}

extern "C" void kernel_launch(void* const* d_in, const int* in_sizes, int n_in,
                              void* d_out, int out_size, void* d_ws, size_t ws_size,
                              hipStream_t stream) {
    const float* x       = (const float*)d_in[0];
    const float* centers = (const float*)d_in[1];
    const float* widths  = (const float*)d_in[2];
    float* out           = (float*)d_out;

    const int total_threads = BATCH * HW;     // 524288 threads, 1 pixel each
    const int block = 256;
    const int grid  = total_threads / block;  // 2048 blocks

    rbf_hist_kernel<<<grid, block, 0, stream>>>(x, centers, widths, out);
}